// Round 3
// baseline (645.491 us; speedup 1.0000x reference)
//
#include <hip/hip_runtime.h>
#include <hip/hip_bf16.h>
#include <math.h>

// DN test-mode forward, split-bf16 MFMA (hi*hi + hi*lo + lo*hi), with:
//  - x pre-split/pre-tiled/pre-swizzled once -> A staged via global_load_lds (no VALU)
//  - W reg-staged + RNE split; ||w_y|| fused into staging (row_norms(Y) kernel deleted)
//  - single 48-MFMA cluster per K-tile with shared fragments

typedef __attribute__((ext_vector_type(8))) short short8;
typedef __attribute__((ext_vector_type(4))) float f32x4;

#define NT 128  // K tiles of 32 f32 columns

__device__ __forceinline__ unsigned short f2bf(float f) {
    union { __hip_bfloat16 b; unsigned short u; } cv;
    cv.b = __float2bfloat16(f);   // RNE
    return cv.u;
}
__device__ __forceinline__ void splitPack2(float f0, float f1, unsigned& h, unsigned& l) {
    const unsigned short h0 = f2bf(f0), h1 = f2bf(f1);
    const float r0 = f0 - __uint_as_float((unsigned)h0 << 16);  // exact (Sterbenz)
    const float r1 = f1 - __uint_as_float((unsigned)h1 << 16);
    h = (unsigned)h0 | ((unsigned)h1 << 16);
    l = (unsigned)f2bf(r0) | ((unsigned)f2bf(r1) << 16);
}

#define GLDS(gp, lp) __builtin_amdgcn_global_load_lds( \
    (const __attribute__((address_space(1))) void*)(gp), \
    (__attribute__((address_space(3))) void*)(lp), 16, 0, 0)

// ---- pre-split x into [t][bx][1024] uint4 tiles, swizzled exactly as the GEMM's LDS wants ----
__global__ __launch_bounds__(512) void split_x(const float* __restrict__ x,
                                               uint4* __restrict__ xhi,
                                               uint4* __restrict__ xlo) {
    const int gid = blockIdx.x * 512 + threadIdx.x;   // 262144 total
    const int t  = gid >> 11;
    const int bx = (gid >> 10) & 1;
    const int li = gid & 1023;
    const int rl = li >> 2;
    const int sp = li & 3;
    const int g  = sp ^ ((rl >> 1) & 3);              // un-swizzle: slot -> k-group
    const float* src = x + (size_t)(bx * 256 + rl) * 4096 + (t << 5) + (g << 3);
    const float4 a = *(const float4*)src;
    const float4 b = *(const float4*)(src + 4);
    uint4 h, l;
    splitPack2(a.x, a.y, h.x, l.x);
    splitPack2(a.z, a.w, h.y, l.y);
    splitPack2(b.x, b.y, h.z, l.z);
    splitPack2(b.z, b.w, h.w, l.w);
    xhi[gid] = h;
    xlo[gid] = l;
}

__global__ __launch_bounds__(256) void row_norms(const float* __restrict__ src,
                                                 float* __restrict__ dst, int cols) {
    const int r = blockIdx.x;
    const float* row = src + (size_t)r * cols;
    const int t = threadIdx.x;
    float s = 0.f;
    const int nIter = cols >> 10;
    for (int i = 0; i < nIter; ++i) {
        const float4 v = *reinterpret_cast<const float4*>(row + (((i << 8) + t) << 2));
        s = fmaf(v.x, v.x, s); s = fmaf(v.y, v.y, s);
        s = fmaf(v.z, v.z, s); s = fmaf(v.w, v.w, s);
    }
    #pragma unroll
    for (int off = 32; off; off >>= 1) s += __shfl_down(s, off);
    __shared__ float red[4];
    if ((t & 63) == 0) red[t >> 6] = s;
    __syncthreads();
    if (t == 0) dst[r] = sqrtf(red[0] + red[1] + red[2] + red[3]);
}

__global__ __launch_bounds__(512, 2) void gemm_argmax(
    const float* __restrict__ w,      // [32768][4096]
    const uint4* __restrict__ xhi,    // [128][2][1024] pre-tiled
    const uint4* __restrict__ xlo,
    const int*  __restrict__ age,     // [32768]
    float2* __restrict__ cand)        // [512][256]
{
    __shared__ uint4 AsHi[2][1024];   // 256 rows x 4 slots (swizzled)
    __shared__ uint4 AsLo[2][1024];
    __shared__ uint4 BsHi[2][512];    // 128 rows x 4 slots
    __shared__ uint4 BsLo[2][512];
    __shared__ float ny_inv[128];
    __shared__ float2 comb[256][2];

    const int tid = threadIdx.x;
    const int bx = blockIdx.x;
    const int b0 = bx << 8;           // BM = 256
    const int y0 = blockIdx.y << 7;   // BN = 128

    // B staging: one 8-f32 slot per thread
    const int rB = tid >> 2, sB = tid & 3;
    const int wiB = (rB << 2) + (sB ^ ((rB >> 1) & 3));
    const float* bP = w + (size_t)(y0 + rB) * 4096 + (sB << 3);
    // A staging: linear DMA
    const int aoff = (bx << 10) + tid;

    // MFMA lane decomposition (wave tile 64x64, 16x16x32 frags)
    const int lane = tid & 63, wave = tid >> 6;
    const int wm = wave >> 1, wn = wave & 1;      // 4 M-waves x 2 N-waves
    const int rl = lane & 15, kg = lane >> 4;
    const int swz = (rl >> 1) & 3;
    const int aBase = (((wm << 6) + rl) << 2) + (kg ^ swz);
    const int bBase = (((wn << 6) + rl) << 2) + (kg ^ swz);

    f32x4 acc[4][4];
    #pragma unroll
    for (int mi = 0; mi < 4; ++mi)
        #pragma unroll
        for (int ni = 0; ni < 4; ++ni) acc[mi][ni] = (f32x4)0.0f;

    float nyacc = 0.0f;
    float4 p0, p1;   // B reg-stage

#define LOADB(t) do { const float* p_ = bP + ((t) << 5); \
    p0 = *(const float4*)p_; p1 = *(const float4*)(p_ + 4); } while (0)

#define STOREB(buf) do { uint4 h_, l_; \
    splitPack2(p0.x, p0.y, h_.x, l_.x); \
    splitPack2(p0.z, p0.w, h_.y, l_.y); \
    splitPack2(p1.x, p1.y, h_.z, l_.z); \
    splitPack2(p1.z, p1.w, h_.w, l_.w); \
    BsHi[buf][wiB] = h_; BsLo[buf][wiB] = l_; \
    nyacc = fmaf(p0.x, p0.x, nyacc); nyacc = fmaf(p0.y, p0.y, nyacc); \
    nyacc = fmaf(p0.z, p0.z, nyacc); nyacc = fmaf(p0.w, p0.w, nyacc); \
    nyacc = fmaf(p1.x, p1.x, nyacc); nyacc = fmaf(p1.y, p1.y, nyacc); \
    nyacc = fmaf(p1.z, p1.z, nyacc); nyacc = fmaf(p1.w, p1.w, nyacc); } while (0)

#define STAGE_A(buf, t) do { \
    const uint4* g0_ = xhi + ((size_t)(t) << 11) + aoff; \
    const uint4* g1_ = xlo + ((size_t)(t) << 11) + aoff; \
    GLDS(g0_,       &AsHi[buf][tid]); \
    GLDS(g0_ + 512, &AsHi[buf][tid + 512]); \
    GLDS(g1_,       &AsLo[buf][tid]); \
    GLDS(g1_ + 512, &AsLo[buf][tid + 512]); } while (0)

#define COMPUTE(buf) do { \
    short8 ah_[4], al_[4], bh_[4], bl_[4]; \
    _Pragma("unroll") for (int i = 0; i < 4; ++i) { \
        ah_[i] = *(const short8*)&AsHi[buf][aBase + (i << 6)]; \
        al_[i] = *(const short8*)&AsLo[buf][aBase + (i << 6)]; \
        bh_[i] = *(const short8*)&BsHi[buf][bBase + (i << 6)]; \
        bl_[i] = *(const short8*)&BsLo[buf][bBase + (i << 6)]; \
    } \
    _Pragma("unroll") for (int mi = 0; mi < 4; ++mi) \
    _Pragma("unroll") for (int ni = 0; ni < 4; ++ni) \
        acc[mi][ni] = __builtin_amdgcn_mfma_f32_16x16x32_bf16(ah_[mi], bh_[ni], acc[mi][ni], 0, 0, 0); \
    _Pragma("unroll") for (int mi = 0; mi < 4; ++mi) \
    _Pragma("unroll") for (int ni = 0; ni < 4; ++ni) \
        acc[mi][ni] = __builtin_amdgcn_mfma_f32_16x16x32_bf16(ah_[mi], bl_[ni], acc[mi][ni], 0, 0, 0); \
    _Pragma("unroll") for (int mi = 0; mi < 4; ++mi) \
    _Pragma("unroll") for (int ni = 0; ni < 4; ++ni) \
        acc[mi][ni] = __builtin_amdgcn_mfma_f32_16x16x32_bf16(al_[mi], bh_[ni], acc[mi][ni], 0, 0, 0); \
} while (0)

    // Prologue: tile 0 into buf 0
    STAGE_A(0, 0);
    LOADB(0);
    STOREB(0);
    __syncthreads();

    for (int t = 0; t < 126; t += 2) {
        LOADB(t + 1); STAGE_A(1, t + 1);
        COMPUTE(0);
        STOREB(1);
        __syncthreads();
        LOADB(t + 2); STAGE_A(0, t + 2);
        COMPUTE(1);
        STOREB(0);
        __syncthreads();
    }
    LOADB(127); STAGE_A(1, 127);
    COMPUTE(0);
    STOREB(1);
    __syncthreads();
    COMPUTE(1);

    // ---- fused ||w_y||: reduce 4 slot-threads per row ----
    float s = nyacc;
    s += __shfl_xor(s, 1);
    s += __shfl_xor(s, 2);
    if (sB == 0) ny_inv[rB] = 1.0f / fmaxf(sqrtf(s), 1e-12f);
    __syncthreads();

    // ---- epilogue: gate + scale + argmax ----
    // acc[mi][ni][j] = S[b0 + wm*64 + mi*16 + 4*kg + j][y0 + wn*64 + ni*16 + rl]
    float scl[4]; int activ[4], ybase[4];
    #pragma unroll
    for (int ni = 0; ni < 4; ++ni) {
        const int yloc = (wn << 6) + (ni << 4) + rl;
        ybase[ni] = y0 + yloc;
        scl[ni] = ny_inv[yloc];
        activ[ni] = (age[y0 + yloc] >= 1);
    }
    #pragma unroll
    for (int mi = 0; mi < 4; ++mi) {
        #pragma unroll
        for (int j = 0; j < 4; ++j) {
            float bv = -INFINITY; int bi = 0x7fffffff;
            #pragma unroll
            for (int ni = 0; ni < 4; ++ni) {   // ascending y -> first-index ties
                const float v = activ[ni] ? acc[mi][ni][j] * scl[ni] : 0.0f;
                if (v > bv) { bv = v; bi = ybase[ni]; }
            }
            #pragma unroll
            for (int off = 1; off < 16; off <<= 1) {
                const float ov = __shfl_xor(bv, off);
                const int   oi = __shfl_xor(bi, off);
                if (ov > bv || (ov == bv && oi < bi)) { bv = ov; bi = oi; }
            }
            if (rl == 0)
                comb[(wm << 6) + (mi << 4) + (kg << 2) + j][wn] = make_float2(bv, __int_as_float(bi));
        }
    }
    __syncthreads();
    if (tid < 256) {
        const float2 e0 = comb[tid][0], e1 = comb[tid][1];
        const int i0 = __float_as_int(e0.y), i1 = __float_as_int(e1.y);
        const bool take1 = (e1.x > e0.x) || (e1.x == e0.x && i1 < i0);
        cand[(size_t)(b0 + tid) * 256 + blockIdx.y] = take1 ? e1 : e0;
    }
#undef LOADB
#undef STOREB
#undef STAGE_A
#undef COMPUTE
}

__global__ __launch_bounds__(256) void reduce_winner(const float2* __restrict__ cand,
                                                     int* __restrict__ winner, int nChunks) {
    const int b = blockIdx.x;
    const int t = threadIdx.x;
    float bv = -INFINITY; int bi = 0x7fffffff;
    for (int c = t; c < nChunks; c += 256) {
        const float2 e = cand[(size_t)b * nChunks + c];
        const int i = __float_as_int(e.y);
        if (e.x > bv || (e.x == bv && i < bi)) { bv = e.x; bi = i; }
    }
    #pragma unroll
    for (int off = 32; off; off >>= 1) {
        const float ov = __shfl_xor(bv, off);
        const int   oi = __shfl_xor(bi, off);
        if (ov > bv || (ov == bv && oi < bi)) { bv = ov; bi = oi; }
    }
    __shared__ float sv[4]; __shared__ int si[4];
    if ((t & 63) == 0) { sv[t >> 6] = bv; si[t >> 6] = bi; }
    __syncthreads();
    if (t == 0) {
        #pragma unroll
        for (int wv = 1; wv < 4; ++wv)
            if (sv[wv] > bv || (sv[wv] == bv && si[wv] < bi)) { bv = sv[wv]; bi = si[wv]; }
        winner[b] = bi;
    }
}

__global__ __launch_bounds__(256) void gather_out(const float* __restrict__ y2z,
                                                  const float* __restrict__ nz,
                                                  const int* __restrict__ winner,
                                                  float* __restrict__ out,
                                                  int B, int Z, int Y) {
    const int g = blockIdx.x * 256 + threadIdx.x;
    if (g >= B * Z) return;
    const int b = g / Z, z = g - b * Z;
    out[g] = y2z[(size_t)z * Y + winner[b]] / fmaxf(nz[z], 1e-12f);
}

extern "C" void kernel_launch(void* const* d_in, const int* in_sizes, int n_in,
                              void* d_out, int out_size, void* d_ws, size_t ws_size,
                              hipStream_t stream) {
    const float* x     = (const float*)d_in[0];
    const float* x2y_w = (const float*)d_in[2];
    const float* y2z_w = (const float*)d_in[3];
    const int*   y_age = (const int*)d_in[4];
    float* out = (float*)d_out;

    const int B = 512, Y = 32768, Z = 1000;
    const int nChunks = 256;

    // ws layout (bytes): cand 1MB | nz 4KB | winner 2KB | xhi 4MB | xlo 4MB
    float2* cand   = (float2*)d_ws;
    float*  nz     = (float*)(cand + (size_t)B * nChunks);
    int*    winner = (int*)(nz + 1024);
    uint4*  xhi    = (uint4*)(winner + 512);
    uint4*  xlo    = xhi + 262144;

    split_x<<<512, 512, 0, stream>>>(x, xhi, xlo);
    row_norms<<<Z, 256, 0, stream>>>(y2z_w, nz, Y);

    gemm_argmax<<<dim3(2, 256), 512, 0, stream>>>(x2y_w, xhi, xlo, y_age, cand);
    reduce_winner<<<B, 256, 0, stream>>>(cand, winner, nChunks);
    gather_out<<<(B * Z + 255) / 256, 256, 0, stream>>>(y2z_w, nz, winner, out, B, Z, Y);
}

// Round 4
// 538.850 us; speedup vs baseline: 1.1979x; 1.1979x over previous
//
#include <hip/hip_runtime.h>
#include <hip/hip_bf16.h>
#include <math.h>

// DN test-mode forward, split-bf16 MFMA (hi*hi + hi*lo + lo*hi):
//  - x pre-split/tiled/swizzled once -> A staged via global_load_lds (no VALU)
//  - W reg-staged 2 tiles deep + RNE split; ||w_y|| fused into staging
//  - raw s_barrier + counted vmcnt(2): A-DMA and W-prefetch survive barriers (T3+T4)
//  - setprio(1) around each 16-MFMA cluster (T5)

typedef __attribute__((ext_vector_type(8))) short short8;
typedef __attribute__((ext_vector_type(4))) float f32x4;

__device__ __forceinline__ unsigned short f2bf(float f) {
    union { __hip_bfloat16 b; unsigned short u; } cv;
    cv.b = __float2bfloat16(f);   // RNE
    return cv.u;
}
__device__ __forceinline__ void splitPack2(float f0, float f1, unsigned& h, unsigned& l) {
    const unsigned short h0 = f2bf(f0), h1 = f2bf(f1);
    const float r0 = f0 - __uint_as_float((unsigned)h0 << 16);  // exact (Sterbenz)
    const float r1 = f1 - __uint_as_float((unsigned)h1 << 16);
    h = (unsigned)h0 | ((unsigned)h1 << 16);
    l = (unsigned)f2bf(r0) | ((unsigned)f2bf(r1) << 16);
}

#define GLDS(gp, lp) __builtin_amdgcn_global_load_lds( \
    (const __attribute__((address_space(1))) void*)(gp), \
    (__attribute__((address_space(3))) void*)(lp), 16, 0, 0)

// ---- pre-split x into [t][bx][1024] uint4 tiles, swizzled as the GEMM's LDS wants ----
__global__ __launch_bounds__(512) void split_x(const float* __restrict__ x,
                                               uint4* __restrict__ xhi,
                                               uint4* __restrict__ xlo) {
    const int gid = blockIdx.x * 512 + threadIdx.x;   // 262144 total
    const int t  = gid >> 11;
    const int bx = (gid >> 10) & 1;
    const int li = gid & 1023;
    const int rl = li >> 2;
    const int sp = li & 3;
    const int g  = sp ^ ((rl >> 1) & 3);              // un-swizzle: slot -> k-group
    const float* src = x + (size_t)(bx * 256 + rl) * 4096 + (t << 5) + (g << 3);
    const float4 a = *(const float4*)src;
    const float4 b = *(const float4*)(src + 4);
    uint4 h, l;
    splitPack2(a.x, a.y, h.x, l.x);
    splitPack2(a.z, a.w, h.y, l.y);
    splitPack2(b.x, b.y, h.z, l.z);
    splitPack2(b.z, b.w, h.w, l.w);
    xhi[gid] = h;
    xlo[gid] = l;
}

__global__ __launch_bounds__(256) void row_norms(const float* __restrict__ src,
                                                 float* __restrict__ dst, int cols) {
    const int r = blockIdx.x;
    const float* row = src + (size_t)r * cols;
    const int t = threadIdx.x;
    float s = 0.f;
    const int nIter = cols >> 10;
    for (int i = 0; i < nIter; ++i) {
        const float4 v = *reinterpret_cast<const float4*>(row + (((i << 8) + t) << 2));
        s = fmaf(v.x, v.x, s); s = fmaf(v.y, v.y, s);
        s = fmaf(v.z, v.z, s); s = fmaf(v.w, v.w, s);
    }
    #pragma unroll
    for (int off = 32; off; off >>= 1) s += __shfl_down(s, off);
    __shared__ float red[4];
    if ((t & 63) == 0) red[t >> 6] = s;
    __syncthreads();
    if (t == 0) dst[r] = sqrtf(red[0] + red[1] + red[2] + red[3]);
}

__global__ __launch_bounds__(512, 2) void gemm_argmax(
    const float* __restrict__ w,      // [32768][4096]
    const uint4* __restrict__ xhi,    // [128][2][1024] pre-tiled
    const uint4* __restrict__ xlo,
    const int*  __restrict__ age,     // [32768]
    float2* __restrict__ cand)        // [512][256]
{
    __shared__ uint4 AsHi[2][1024];   // 256 rows x 4 slots (swizzled)
    __shared__ uint4 AsLo[2][1024];
    __shared__ uint4 BsHi[2][512];    // 128 rows x 4 slots
    __shared__ uint4 BsLo[2][512];
    __shared__ float ny_inv[128];
    __shared__ float2 comb[256][2];

    const int tid = threadIdx.x;
    const int bx = blockIdx.x;
    const int b0 = bx << 8;           // BM = 256
    const int y0 = blockIdx.y << 7;   // BN = 128

    // B staging: one 8-f32 slot per thread
    const int rB = tid >> 2, sB = tid & 3;
    const int wiB = (rB << 2) + (sB ^ ((rB >> 1) & 3));
    const float* bP = w + (size_t)(y0 + rB) * 4096 + (sB << 3);
    // A staging: linear DMA
    const int aoff = (bx << 10) + tid;

    // MFMA lane decomposition (wave tile 64x64, 16x16x32 frags)
    const int lane = tid & 63, wave = tid >> 6;
    const int wm = wave >> 1, wn = wave & 1;      // 4 M-waves x 2 N-waves
    const int rl = lane & 15, kg = lane >> 4;
    const int swz = (rl >> 1) & 3;
    const int aBase = (((wm << 6) + rl) << 2) + (kg ^ swz);
    const int bBase = (((wn << 6) + rl) << 2) + (kg ^ swz);

    f32x4 acc[4][4];
    #pragma unroll
    for (int mi = 0; mi < 4; ++mi)
        #pragma unroll
        for (int ni = 0; ni < 4; ++ni) acc[mi][ni] = (f32x4)0.0f;

    float nyacc = 0.0f;
    float4 P0a, P0b, P1a, P1b;   // two B reg-stage sets (B(k) lives in set k&1)

#define STAGE_A(buf, t) do { \
    const uint4* g0_ = xhi + ((size_t)(t) << 11) + aoff; \
    const uint4* g1_ = xlo + ((size_t)(t) << 11) + aoff; \
    GLDS(g0_,       &AsHi[buf][tid]); \
    GLDS(g0_ + 512, &AsHi[buf][tid + 512]); \
    GLDS(g1_,       &AsLo[buf][tid]); \
    GLDS(g1_ + 512, &AsLo[buf][tid + 512]); } while (0)

#define LOADB(Ra, Rb, t) do { const float* p_ = bP + ((t) << 5); \
    Ra = *(const float4*)p_; Rb = *(const float4*)(p_ + 4); } while (0)

#define STOREB(buf, Pa, Pb) do { uint4 h_, l_; \
    splitPack2(Pa.x, Pa.y, h_.x, l_.x); \
    splitPack2(Pa.z, Pa.w, h_.y, l_.y); \
    splitPack2(Pb.x, Pb.y, h_.z, l_.z); \
    splitPack2(Pb.z, Pb.w, h_.w, l_.w); \
    BsHi[buf][wiB] = h_; BsLo[buf][wiB] = l_; \
    nyacc = fmaf(Pa.x, Pa.x, nyacc); nyacc = fmaf(Pa.y, Pa.y, nyacc); \
    nyacc = fmaf(Pa.z, Pa.z, nyacc); nyacc = fmaf(Pa.w, Pa.w, nyacc); \
    nyacc = fmaf(Pb.x, Pb.x, nyacc); nyacc = fmaf(Pb.y, Pb.y, nyacc); \
    nyacc = fmaf(Pb.z, Pb.z, nyacc); nyacc = fmaf(Pb.w, Pb.w, nyacc); } while (0)

#define MM16(A_, B_) \
    _Pragma("unroll") for (int mi = 0; mi < 4; ++mi) \
    _Pragma("unroll") for (int ni = 0; ni < 4; ++ni) \
        acc[mi][ni] = __builtin_amdgcn_mfma_f32_16x16x32_bf16(A_[mi], B_[ni], acc[mi][ni], 0, 0, 0)

// 3 pairings; B-convert/publish sits between cluster 1 and 2 so other waves'
// MFMA overlaps this wave's VALU. bh re-read for pairing 3 caps live VGPRs.
#define PHASES(buf, STOREB_STMT) do { \
    short8 fa[4], fb[4]; \
    _Pragma("unroll") for (int i = 0; i < 4; ++i) fa[i] = *(const short8*)&AsHi[buf][aBase + (i << 6)]; \
    _Pragma("unroll") for (int i = 0; i < 4; ++i) fb[i] = *(const short8*)&BsHi[buf][bBase + (i << 6)]; \
    __builtin_amdgcn_s_setprio(1); MM16(fa, fb); __builtin_amdgcn_s_setprio(0); \
    STOREB_STMT; \
    _Pragma("unroll") for (int i = 0; i < 4; ++i) fb[i] = *(const short8*)&BsLo[buf][bBase + (i << 6)]; \
    __builtin_amdgcn_s_setprio(1); MM16(fa, fb); __builtin_amdgcn_s_setprio(0); \
    _Pragma("unroll") for (int i = 0; i < 4; ++i) fa[i] = *(const short8*)&AsLo[buf][aBase + (i << 6)]; \
    _Pragma("unroll") for (int i = 0; i < 4; ++i) fb[i] = *(const short8*)&BsHi[buf][bBase + (i << 6)]; \
    __builtin_amdgcn_s_setprio(1); MM16(fa, fb); __builtin_amdgcn_s_setprio(0); \
} while (0)

#define SB __builtin_amdgcn_sched_barrier(0)

// One K-tile: pin issue order [GLDS x4][B-load x2][phases][lgkm0 vmcnt(2) barrier].
// vmcnt(2) retires the 4 GLDS (FIFO), leaves the 2 newest B-loads in flight.
#define BODY(cur, tt, RLa, RLb, RSa, RSb) do { \
    SB; \
    STAGE_A((cur) ^ 1, (tt) + 1); \
    SB; \
    LOADB(RLa, RLb, (tt) + 2); \
    SB; \
    PHASES(cur, STOREB((cur) ^ 1, RSa, RSb)); \
    SB; \
    asm volatile("s_waitcnt lgkmcnt(0)" ::: "memory"); \
    asm volatile("s_waitcnt vmcnt(2)" ::: "memory"); \
    SB; \
    __builtin_amdgcn_s_barrier(); \
} while (0)

    // ---- prologue: stage tile 0, preload B(0),B(1) ----
    STAGE_A(0, 0);
    SB;
    LOADB(P0a, P0b, 0);
    LOADB(P1a, P1b, 1);
    SB;
    STOREB(0, P0a, P0b);     // compiler vmcnt wait drains GLDS(0) + B(0), leaves B(1)
    SB;
    asm volatile("s_waitcnt lgkmcnt(0)" ::: "memory");
    SB;
    __builtin_amdgcn_s_barrier();

    for (int t = 0; t < 126; t += 2) {
        BODY(0, t,     P0a, P0b, P1a, P1b);   // load B(t+2)->P0, publish B(t+1) from P1
        BODY(1, t + 1, P1a, P1b, P0a, P0b);
    }
    // ---- tail: t=126 (cur=0, stage A(127), publish B(127)), then t=127 ----
    SB;
    STAGE_A(1, 127);
    SB;
    PHASES(0, STOREB(1, P1a, P1b));
    SB;
    asm volatile("s_waitcnt lgkmcnt(0)" ::: "memory");
    asm volatile("s_waitcnt vmcnt(0)" ::: "memory");
    SB;
    __builtin_amdgcn_s_barrier();
    PHASES(1, (void)0);

    // ---- fused ||w_y||: reduce 4 slot-threads per row ----
    float s = nyacc;
    s += __shfl_xor(s, 1);
    s += __shfl_xor(s, 2);
    if (sB == 0) ny_inv[rB] = 1.0f / fmaxf(sqrtf(s), 1e-12f);
    __syncthreads();

    // ---- epilogue: gate + scale + argmax ----
    // acc[mi][ni][j] = S[b0 + wm*64 + mi*16 + 4*kg + j][y0 + wn*64 + ni*16 + rl]
    float scl[4]; int activ[4], ybase[4];
    #pragma unroll
    for (int ni = 0; ni < 4; ++ni) {
        const int yloc = (wn << 6) + (ni << 4) + rl;
        ybase[ni] = y0 + yloc;
        scl[ni] = ny_inv[yloc];
        activ[ni] = (age[y0 + yloc] >= 1);
    }
    #pragma unroll
    for (int mi = 0; mi < 4; ++mi) {
        #pragma unroll
        for (int j = 0; j < 4; ++j) {
            float bv = -INFINITY; int bi = 0x7fffffff;
            #pragma unroll
            for (int ni = 0; ni < 4; ++ni) {   // ascending y -> first-index ties
                const float v = activ[ni] ? acc[mi][ni][j] * scl[ni] : 0.0f;
                if (v > bv) { bv = v; bi = ybase[ni]; }
            }
            #pragma unroll
            for (int off = 1; off < 16; off <<= 1) {
                const float ov = __shfl_xor(bv, off);
                const int   oi = __shfl_xor(bi, off);
                if (ov > bv || (ov == bv && oi < bi)) { bv = ov; bi = oi; }
            }
            if (rl == 0)
                comb[(wm << 6) + (mi << 4) + (kg << 2) + j][wn] = make_float2(bv, __int_as_float(bi));
        }
    }
    __syncthreads();
    if (tid < 256) {
        const float2 e0 = comb[tid][0], e1 = comb[tid][1];
        const int i0 = __float_as_int(e0.y), i1 = __float_as_int(e1.y);
        const bool take1 = (e1.x > e0.x) || (e1.x == e0.x && i1 < i0);
        cand[(size_t)(b0 + tid) * 256 + blockIdx.y] = take1 ? e1 : e0;
    }
#undef STAGE_A
#undef LOADB
#undef STOREB
#undef MM16
#undef PHASES
#undef SB
#undef BODY
}

__global__ __launch_bounds__(256) void reduce_winner(const float2* __restrict__ cand,
                                                     int* __restrict__ winner, int nChunks) {
    const int b = blockIdx.x;
    const int t = threadIdx.x;
    float bv = -INFINITY; int bi = 0x7fffffff;
    for (int c = t; c < nChunks; c += 256) {
        const float2 e = cand[(size_t)b * nChunks + c];
        const int i = __float_as_int(e.y);
        if (e.x > bv || (e.x == bv && i < bi)) { bv = e.x; bi = i; }
    }
    #pragma unroll
    for (int off = 32; off; off >>= 1) {
        const float ov = __shfl_xor(bv, off);
        const int   oi = __shfl_xor(bi, off);
        if (ov > bv || (ov == bv && oi < bi)) { bv = ov; bi = oi; }
    }
    __shared__ float sv[4]; __shared__ int si[4];
    if ((t & 63) == 0) { sv[t >> 6] = bv; si[t >> 6] = bi; }
    __syncthreads();
    if (t == 0) {
        #pragma unroll
        for (int wv = 1; wv < 4; ++wv)
            if (sv[wv] > bv || (sv[wv] == bv && si[wv] < bi)) { bv = sv[wv]; bi = si[wv]; }
        winner[b] = bi;
    }
}

__global__ __launch_bounds__(256) void gather_out(const float* __restrict__ y2z,
                                                  const float* __restrict__ nz,
                                                  const int* __restrict__ winner,
                                                  float* __restrict__ out,
                                                  int B, int Z, int Y) {
    const int g = blockIdx.x * 256 + threadIdx.x;
    if (g >= B * Z) return;
    const int b = g / Z, z = g - b * Z;
    out[g] = y2z[(size_t)z * Y + winner[b]] / fmaxf(nz[z], 1e-12f);
}

extern "C" void kernel_launch(void* const* d_in, const int* in_sizes, int n_in,
                              void* d_out, int out_size, void* d_ws, size_t ws_size,
                              hipStream_t stream) {
    const float* x     = (const float*)d_in[0];
    const float* x2y_w = (const float*)d_in[2];
    const float* y2z_w = (const float*)d_in[3];
    const int*   y_age = (const int*)d_in[4];
    float* out = (float*)d_out;

    const int B = 512, Y = 32768, Z = 1000;
    const int nChunks = 256;

    // ws layout: cand 1MB | nz 4KB | winner 2KB | xhi 4MB | xlo 4MB
    float2* cand   = (float2*)d_ws;
    float*  nz     = (float*)(cand + (size_t)B * nChunks);
    int*    winner = (int*)(nz + 1024);
    uint4*  xhi    = (uint4*)(winner + 512);
    uint4*  xlo    = xhi + 262144;

    split_x<<<512, 512, 0, stream>>>(x, xhi, xlo);
    row_norms<<<Z, 256, 0, stream>>>(y2z_w, nz, Y);

    gemm_argmax<<<dim3(2, 256), 512, 0, stream>>>(x2y_w, xhi, xlo, y_age, cand);
    reduce_winner<<<B, 256, 0, stream>>>(cand, winner, nChunks);
    gather_out<<<(B * Z + 255) / 256, 256, 0, stream>>>(y2z_w, nz, winner, out, B, Z, Y);
}

// Round 5
// 518.491 us; speedup vs baseline: 1.2449x; 1.0393x over previous
//
#include <hip/hip_runtime.h>
#include <hip/hip_bf16.h>
#include <math.h>

// DN test-mode forward, split-bf16 via 32x32x16 MFMA (hh + hl + lh pairings):
//  - x pre-split into per-wave fragment-contiguous hi/lo tiles -> A global->VGPR,
//    no LDS for A, A-hi prefetched 1 tile ahead, A-lo loaded intra-tile
//  - W reg-staged + RNE split into LDS (B only, 32KB dbuf); ||w_y|| fused
//  - one lgkmcnt(0)+s_barrier per K-tile; compiler-managed vmcnt keeps
//    prefetches in flight across barriers; setprio around MFMA clusters

typedef __attribute__((ext_vector_type(8)))  short short8;
typedef __attribute__((ext_vector_type(16))) float f32x16;

__device__ __forceinline__ unsigned short f2bf(float f) {
    union { __hip_bfloat16 b; unsigned short u; } cv;
    cv.b = __float2bfloat16(f);   // RNE
    return cv.u;
}
__device__ __forceinline__ void splitPack2(float f0, float f1, unsigned& h, unsigned& l) {
    const unsigned short h0 = f2bf(f0), h1 = f2bf(f1);
    const float r0 = f0 - __uint_as_float((unsigned)h0 << 16);  // exact (Sterbenz)
    const float r1 = f1 - __uint_as_float((unsigned)h1 << 16);
    h = (unsigned)h0 | ((unsigned)h1 << 16);
    l = (unsigned)f2bf(r0) | ((unsigned)f2bf(r1) << 16);
}

// x pre-split layout: o = (t<<11)|(bx<<10)|(wm<<8)|(mi<<7)|(ks<<6)|lane  (uint4 units)
// lane's 16B = bf16 x8 of row bx*256+wm*64+mi*32+(lane&31), cols t*32+ks*16+(lane>>5)*8..
__global__ __launch_bounds__(512) void split_x(const float* __restrict__ x,
                                               uint4* __restrict__ xhi,
                                               uint4* __restrict__ xlo) {
    const int o = blockIdx.x * 512 + threadIdx.x;   // 262144 outputs per buffer
    const int l  = o & 63;
    const int ks = (o >> 6) & 1;
    const int mi = (o >> 7) & 1;
    const int wm = (o >> 8) & 3;
    const int bx = (o >> 10) & 1;
    const int t  = o >> 11;
    const int row = (bx << 8) + (wm << 6) + (mi << 5) + (l & 31);
    const int col = (t << 5) + (ks << 4) + ((l >> 5) << 3);
    const float* src = x + (size_t)row * 4096 + col;
    const float4 a = *(const float4*)src;
    const float4 b = *(const float4*)(src + 4);
    uint4 h, lo;
    splitPack2(a.x, a.y, h.x, lo.x);
    splitPack2(a.z, a.w, h.y, lo.y);
    splitPack2(b.x, b.y, h.z, lo.z);
    splitPack2(b.z, b.w, h.w, lo.w);
    xhi[o] = h;
    xlo[o] = lo;
}

__global__ __launch_bounds__(256) void row_norms(const float* __restrict__ src,
                                                 float* __restrict__ dst, int cols) {
    const int r = blockIdx.x;
    const float* row = src + (size_t)r * cols;
    const int t = threadIdx.x;
    float s = 0.f;
    const int nIter = cols >> 10;
    for (int i = 0; i < nIter; ++i) {
        const float4 v = *reinterpret_cast<const float4*>(row + (((i << 8) + t) << 2));
        s = fmaf(v.x, v.x, s); s = fmaf(v.y, v.y, s);
        s = fmaf(v.z, v.z, s); s = fmaf(v.w, v.w, s);
    }
    #pragma unroll
    for (int off = 32; off; off >>= 1) s += __shfl_down(s, off);
    __shared__ float red[4];
    if ((t & 63) == 0) red[t >> 6] = s;
    __syncthreads();
    if (t == 0) dst[r] = sqrtf(red[0] + red[1] + red[2] + red[3]);
}

__global__ __launch_bounds__(512, 2) void gemm_argmax(
    const float* __restrict__ w,      // [32768][4096]
    const uint4* __restrict__ xhi,    // pre-split x, fragment order
    const uint4* __restrict__ xlo,
    const int*  __restrict__ age,     // [32768]
    float2* __restrict__ cand)        // [512][256]
{
    __shared__ uint4 BsHi[2][512];    // 128 rows x 4 swizzled 16B slots
    __shared__ uint4 BsLo[2][512];
    __shared__ float ny_inv[128];
    __shared__ float2 comb[256][2];

    const int tid = threadIdx.x;
    const int bx = blockIdx.x;
    const int b0 = bx << 8;           // BM = 256
    const int y0 = blockIdx.y << 7;   // BN = 128

    // B staging: one 8-f32 slot per thread
    const int rB = tid >> 2, sB = tid & 3;
    const int wiB = (rB << 2) + (sB ^ ((rB >> 1) & 3));
    const float* bP = w + (size_t)(y0 + rB) * 4096 + (sB << 3);

    // MFMA decomposition: 8 waves = 4 wm x 2 wn, wave tile 64x64, 32x32x16 frags
    const int lane = tid & 63, wave = tid >> 6;
    const int wm = wave >> 1, wn = wave & 1;
    const int kh = lane >> 5;                       // k-half within 16-col slice
    const uint4* ah_p = xhi + (bx << 10) + (wm << 8) + lane;
    const uint4* al_p = xlo + (bx << 10) + (wm << 8) + lane;

    // B LDS read indices per (ni, ks)
    const int rr0 = (wn << 6) + (lane & 31);
    const int rr1 = rr0 + 32;
    const int iB00 = (rr0 << 2) + (((0 << 1) | kh) ^ ((rr0 >> 1) & 3));
    const int iB01 = (rr0 << 2) + (((1 << 1) | kh) ^ ((rr0 >> 1) & 3));
    const int iB10 = (rr1 << 2) + (((0 << 1) | kh) ^ ((rr1 >> 1) & 3));
    const int iB11 = (rr1 << 2) + (((1 << 1) | kh) ^ ((rr1 >> 1) & 3));

    f32x16 acc00 = (f32x16)0.0f, acc01 = (f32x16)0.0f;
    f32x16 acc10 = (f32x16)0.0f, acc11 = (f32x16)0.0f;

    short8 A000, A001, A010, A011, A100, A101, A110, A111;  // A-hi, 2 sets
    short8 al00, al01, al10, al11;                          // A-lo, current
    short8 bh00, bh01, bh10, bh11, bl00, bl01, bl10, bl11;  // B frags
    float4 PAa, PAb, PBa, PBb;                              // B reg-stage sets
    float nyacc = 0.0f;

#define MF(a, b, c) __builtin_amdgcn_mfma_f32_32x32x16_bf16(a, b, c, 0, 0, 0)

#define LOADAH(S, tt) do { const uint4* p_ = ah_p + ((size_t)(tt) << 11); \
    S##00 = *(const short8*)(p_);       S##01 = *(const short8*)(p_ + 64); \
    S##10 = *(const short8*)(p_ + 128); S##11 = *(const short8*)(p_ + 192); } while (0)

#define LOADAL(tt) do { const uint4* p_ = al_p + ((size_t)(tt) << 11); \
    al00 = *(const short8*)(p_);       al01 = *(const short8*)(p_ + 64); \
    al10 = *(const short8*)(p_ + 128); al11 = *(const short8*)(p_ + 192); } while (0)

#define LOADB(P, tt) do { const float* p_ = bP + ((tt) << 5); \
    P##a = *(const float4*)p_; P##b = *(const float4*)(p_ + 4); } while (0)

#define STOREB(buf, P) do { uint4 h_, l_; \
    splitPack2(P##a.x, P##a.y, h_.x, l_.x); \
    splitPack2(P##a.z, P##a.w, h_.y, l_.y); \
    splitPack2(P##b.x, P##b.y, h_.z, l_.z); \
    splitPack2(P##b.z, P##b.w, h_.w, l_.w); \
    BsHi[buf][wiB] = h_; BsLo[buf][wiB] = l_; \
    nyacc = fmaf(P##a.x, P##a.x, nyacc); nyacc = fmaf(P##a.y, P##a.y, nyacc); \
    nyacc = fmaf(P##a.z, P##a.z, nyacc); nyacc = fmaf(P##a.w, P##a.w, nyacc); \
    nyacc = fmaf(P##b.x, P##b.x, nyacc); nyacc = fmaf(P##b.y, P##b.y, nyacc); \
    nyacc = fmaf(P##b.z, P##b.z, nyacc); nyacc = fmaf(P##b.w, P##b.w, nyacc); } while (0)

#define LDB(buf) do { \
    bh00 = *(const short8*)&BsHi[buf][iB00]; bh01 = *(const short8*)&BsHi[buf][iB01]; \
    bh10 = *(const short8*)&BsHi[buf][iB10]; bh11 = *(const short8*)&BsHi[buf][iB11]; \
    bl00 = *(const short8*)&BsLo[buf][iB00]; bl01 = *(const short8*)&BsLo[buf][iB01]; \
    bl10 = *(const short8*)&BsLo[buf][iB10]; bl11 = *(const short8*)&BsLo[buf][iB11]; } while (0)

// acc{mi}{ni} += A{mi}{ks} * B{ni}{ks}, ks = 0,1
#define CLUSTER(AP, BP) do { \
    __builtin_amdgcn_s_setprio(1); \
    acc00 = MF(AP##00, BP##00, acc00); acc00 = MF(AP##01, BP##01, acc00); \
    acc01 = MF(AP##00, BP##10, acc01); acc01 = MF(AP##01, BP##11, acc01); \
    acc10 = MF(AP##10, BP##00, acc10); acc10 = MF(AP##11, BP##01, acc10); \
    acc11 = MF(AP##10, BP##10, acc11); acc11 = MF(AP##11, BP##11, acc11); \
    __builtin_amdgcn_s_setprio(0); } while (0)

#define TILE(cur, tt, Scur, Snext, Pst, Pld) do { \
    LOADAL(tt); \
    if ((tt) + 1 < 128) LOADAH(Snext, (tt) + 1); \
    if ((tt) + 2 < 128) LOADB(Pld, (tt) + 2); \
    LDB(cur); \
    CLUSTER(Scur, bh); \
    if ((tt) + 1 < 128) STOREB((cur) ^ 1, Pst); \
    CLUSTER(Scur, bl); \
    CLUSTER(al, bh); \
    __builtin_amdgcn_sched_barrier(0); \
    asm volatile("s_waitcnt lgkmcnt(0)" ::: "memory"); \
    __builtin_amdgcn_sched_barrier(0); \
    __builtin_amdgcn_s_barrier(); \
} while (0)

    // ---- prologue ----
    LOADAH(A0, 0);
    LOADB(PA, 0);
    LOADB(PB, 1);
    STOREB(0, PA);
    __builtin_amdgcn_sched_barrier(0);
    asm volatile("s_waitcnt lgkmcnt(0)" ::: "memory");
    __builtin_amdgcn_sched_barrier(0);
    __builtin_amdgcn_s_barrier();

    for (int t = 0; t < 128; t += 2) {
        TILE(0, t,     A0, A1, PB, PA);   // publish B(t+1) from PB, load B(t+2)->PA
        TILE(1, t + 1, A1, A0, PA, PB);
    }

    // ---- fused ||w_y||: reduce 4 slot-threads per row ----
    float s = nyacc;
    s += __shfl_xor(s, 1);
    s += __shfl_xor(s, 2);
    if (sB == 0) ny_inv[rB] = 1.0f / fmaxf(sqrtf(s), 1e-12f);
    __syncthreads();

    // ---- epilogue: gate + scale + argmax ----
    // 32x32 C/D: value v of acc{mi}{ni} = S[row (v&3)+8*(v>>2)+4*(lane>>5)][col lane&31]
    const int yloc0 = (wn << 6) + (lane & 31);
    const int yloc1 = yloc0 + 32;
    const float scl0 = ny_inv[yloc0], scl1 = ny_inv[yloc1];
    const int act0 = (age[y0 + yloc0] >= 1), act1 = (age[y0 + yloc1] >= 1);
    const int yb0 = y0 + yloc0, yb1 = y0 + yloc1;
    const int rbase = (wm << 6) + ((lane >> 5) << 2);

#define ARGMAX_MI(ACC0, ACC1, mibase) do { \
    _Pragma("unroll") for (int v = 0; v < 16; ++v) { \
        float bv = act0 ? ACC0[v] * scl0 : 0.0f; int bi = yb0; \
        const float v1 = act1 ? ACC1[v] * scl1 : 0.0f; \
        if (v1 > bv) { bv = v1; bi = yb1; } \
        _Pragma("unroll") for (int off = 1; off < 32; off <<= 1) { \
            const float ov = __shfl_xor(bv, off); \
            const int   oi = __shfl_xor(bi, off); \
            if (ov > bv || (ov == bv && oi < bi)) { bv = ov; bi = oi; } \
        } \
        if ((lane & 31) == 0) \
            comb[rbase + (mibase) + (v & 3) + ((v >> 2) << 3)][wn] = \
                make_float2(bv, __int_as_float(bi)); \
    } } while (0)

    ARGMAX_MI(acc00, acc01, 0);
    ARGMAX_MI(acc10, acc11, 32);

    __syncthreads();
    if (tid < 256) {
        const float2 e0 = comb[tid][0], e1 = comb[tid][1];
        const int i0 = __float_as_int(e0.y), i1 = __float_as_int(e1.y);
        const bool take1 = (e1.x > e0.x) || (e1.x == e0.x && i1 < i0);
        cand[(size_t)(b0 + tid) * 256 + blockIdx.y] = take1 ? e1 : e0;
    }
#undef MF
#undef LOADAH
#undef LOADAL
#undef LOADB
#undef STOREB
#undef LDB
#undef CLUSTER
#undef TILE
#undef ARGMAX_MI
}

__global__ __launch_bounds__(256) void reduce_winner(const float2* __restrict__ cand,
                                                     int* __restrict__ winner, int nChunks) {
    const int b = blockIdx.x;
    const int t = threadIdx.x;
    float bv = -INFINITY; int bi = 0x7fffffff;
    for (int c = t; c < nChunks; c += 256) {
        const float2 e = cand[(size_t)b * nChunks + c];
        const int i = __float_as_int(e.y);
        if (e.x > bv || (e.x == bv && i < bi)) { bv = e.x; bi = i; }
    }
    #pragma unroll
    for (int off = 32; off; off >>= 1) {
        const float ov = __shfl_xor(bv, off);
        const int   oi = __shfl_xor(bi, off);
        if (ov > bv || (ov == bv && oi < bi)) { bv = ov; bi = oi; }
    }
    __shared__ float sv[4]; __shared__ int si[4];
    if ((t & 63) == 0) { sv[t >> 6] = bv; si[t >> 6] = bi; }
    __syncthreads();
    if (t == 0) {
        #pragma unroll
        for (int wv = 1; wv < 4; ++wv)
            if (sv[wv] > bv || (sv[wv] == bv && si[wv] < bi)) { bv = sv[wv]; bi = si[wv]; }
        winner[b] = bi;
    }
}

__global__ __launch_bounds__(256) void gather_out(const float* __restrict__ y2z,
                                                  const float* __restrict__ nz,
                                                  const int* __restrict__ winner,
                                                  float* __restrict__ out,
                                                  int B, int Z, int Y) {
    const int g = blockIdx.x * 256 + threadIdx.x;
    if (g >= B * Z) return;
    const int b = g / Z, z = g - b * Z;
    out[g] = y2z[(size_t)z * Y + winner[b]] / fmaxf(nz[z], 1e-12f);
}

extern "C" void kernel_launch(void* const* d_in, const int* in_sizes, int n_in,
                              void* d_out, int out_size, void* d_ws, size_t ws_size,
                              hipStream_t stream) {
    const float* x     = (const float*)d_in[0];
    const float* x2y_w = (const float*)d_in[2];
    const float* y2z_w = (const float*)d_in[3];
    const int*   y_age = (const int*)d_in[4];
    float* out = (float*)d_out;

    const int B = 512, Y = 32768, Z = 1000;
    const int nChunks = 256;

    // ws layout: cand 1MB | nz 4KB | winner 2KB | xhi 4MB | xlo 4MB
    float2* cand   = (float2*)d_ws;
    float*  nz     = (float*)(cand + (size_t)B * nChunks);
    int*    winner = (int*)(nz + 1024);
    uint4*  xhi    = (uint4*)(winner + 512);
    uint4*  xlo    = xhi + 262144;

    split_x<<<512, 512, 0, stream>>>(x, xhi, xlo);
    row_norms<<<Z, 256, 0, stream>>>(y2z_w, nz, Y);

    gemm_argmax<<<dim3(2, 256), 512, 0, stream>>>(x2y_w, xhi, xlo, y_age, cand);
    reduce_winner<<<B, 256, 0, stream>>>(cand, winner, nChunks);
    gather_out<<<(B * Z + 255) / 256, 256, 0, stream>>>(y2z_w, nz, winner, out, B, Z, Y);
}

// Round 6
// 471.987 us; speedup vs baseline: 1.3676x; 1.0985x over previous
//
#include <hip/hip_runtime.h>
#include <hip/hip_bf16.h>
#include <math.h>

// DN test-mode forward, split-bf16 via 32x32x16 MFMA (hh + hl + lh pairings),
// 3-phase-per-K-tile schedule (m201-style): each phase =
//   {ds_read subtile || issue global prefetch -> s_barrier -> lgkmcnt(0) ->
//    setprio(1) 8xMFMA setprio(0) -> s_barrier}
// A (x-side) pre-split/fragment-ordered, global->VGPR (no LDS); B (W-side)
// reg-staged + RNE split into dbuf LDS; ||w_y|| fused into staging.

typedef __attribute__((ext_vector_type(8)))  short short8;
typedef __attribute__((ext_vector_type(16))) float f32x16;

__device__ __forceinline__ unsigned short f2bf(float f) {
    union { __hip_bfloat16 b; unsigned short u; } cv;
    cv.b = __float2bfloat16(f);   // RNE
    return cv.u;
}
__device__ __forceinline__ void splitPack2(float f0, float f1, unsigned& h, unsigned& l) {
    const unsigned short h0 = f2bf(f0), h1 = f2bf(f1);
    const float r0 = f0 - __uint_as_float((unsigned)h0 << 16);  // exact (Sterbenz)
    const float r1 = f1 - __uint_as_float((unsigned)h1 << 16);
    h = (unsigned)h0 | ((unsigned)h1 << 16);
    l = (unsigned)f2bf(r0) | ((unsigned)f2bf(r1) << 16);
}

// x pre-split layout: o = (t<<11)|(bx<<10)|(wm<<8)|(mi<<7)|(ks<<6)|lane (uint4 units)
__global__ __launch_bounds__(512) void split_x(const float* __restrict__ x,
                                               uint4* __restrict__ xhi,
                                               uint4* __restrict__ xlo) {
    const int o = blockIdx.x * 512 + threadIdx.x;   // 262144 outputs per buffer
    const int l  = o & 63;
    const int ks = (o >> 6) & 1;
    const int mi = (o >> 7) & 1;
    const int wm = (o >> 8) & 3;
    const int bx = (o >> 10) & 1;
    const int t  = o >> 11;
    const int row = (bx << 8) + (wm << 6) + (mi << 5) + (l & 31);
    const int col = (t << 5) + (ks << 4) + ((l >> 5) << 3);
    const float* src = x + (size_t)row * 4096 + col;
    const float4 a = *(const float4*)src;
    const float4 b = *(const float4*)(src + 4);
    uint4 h, lo;
    splitPack2(a.x, a.y, h.x, lo.x);
    splitPack2(a.z, a.w, h.y, lo.y);
    splitPack2(b.x, b.y, h.z, lo.z);
    splitPack2(b.z, b.w, h.w, lo.w);
    xhi[o] = h;
    xlo[o] = lo;
}

__global__ __launch_bounds__(256) void row_norms(const float* __restrict__ src,
                                                 float* __restrict__ dst, int cols) {
    const int r = blockIdx.x;
    const float* row = src + (size_t)r * cols;
    const int t = threadIdx.x;
    float s = 0.f;
    const int nIter = cols >> 10;
    for (int i = 0; i < nIter; ++i) {
        const float4 v = *reinterpret_cast<const float4*>(row + (((i << 8) + t) << 2));
        s = fmaf(v.x, v.x, s); s = fmaf(v.y, v.y, s);
        s = fmaf(v.z, v.z, s); s = fmaf(v.w, v.w, s);
    }
    #pragma unroll
    for (int off = 32; off; off >>= 1) s += __shfl_down(s, off);
    __shared__ float red[4];
    if ((t & 63) == 0) red[t >> 6] = s;
    __syncthreads();
    if (t == 0) dst[r] = sqrtf(red[0] + red[1] + red[2] + red[3]);
}

__global__ __launch_bounds__(512, 2) void gemm_argmax(
    const float* __restrict__ w,      // [32768][4096]
    const uint4* __restrict__ xhi,    // pre-split x, fragment order
    const uint4* __restrict__ xlo,
    const int*  __restrict__ age,     // [32768]
    float2* __restrict__ cand)        // [512][256]
{
    __shared__ uint4 BsHi[2][512];    // 128 rows x 4 swizzled 16B slots
    __shared__ uint4 BsLo[2][512];
    __shared__ float ny_inv[128];
    __shared__ float2 comb[256][2];

    const int tid = threadIdx.x;
    const int bx = blockIdx.x;
    const int b0 = bx << 8;           // BM = 256
    const int y0 = blockIdx.y << 7;   // BN = 128

    // B staging: one 8-f32 slot per thread
    const int rB = tid >> 2, sB = tid & 3;
    const int wiB = (rB << 2) + (sB ^ ((rB >> 1) & 3));
    const float* bP = w + (size_t)(y0 + rB) * 4096 + (sB << 3);

    // MFMA decomposition: 8 waves = 4 wm x 2 wn, wave tile 64x64, 32x32x16 frags
    const int lane = tid & 63, wave = tid >> 6;
    const int wm = wave >> 1, wn = wave & 1;
    const int kh = lane >> 5;
    const uint4* ah_p = xhi + (bx << 10) + (wm << 8) + lane;
    const uint4* al_p = xlo + (bx << 10) + (wm << 8) + lane;

    // B LDS read indices per (ni, ks)
    const int rr0 = (wn << 6) + (lane & 31);
    const int rr1 = rr0 + 32;
    const int iB00 = (rr0 << 2) + (((0 << 1) | kh) ^ ((rr0 >> 1) & 3));
    const int iB01 = (rr0 << 2) + (((1 << 1) | kh) ^ ((rr0 >> 1) & 3));
    const int iB10 = (rr1 << 2) + (((0 << 1) | kh) ^ ((rr1 >> 1) & 3));
    const int iB11 = (rr1 << 2) + (((1 << 1) | kh) ^ ((rr1 >> 1) & 3));

    f32x16 acc00 = (f32x16)0.0f, acc01 = (f32x16)0.0f;
    f32x16 acc10 = (f32x16)0.0f, acc11 = (f32x16)0.0f;

    // static register sets (rule #20: no runtime indexing)
    short8 X000, X001, X010, X011, X100, X101, X110, X111;  // A-hi sets 0/1
    short8 L000, L001, L010, L011, L100, L101, L110, L111;  // A-lo sets 0/1
    short8 bh00, bh01, bh10, bh11, bl00, bl01, bl10, bl11;  // B frags
    float4 P0a, P0b, P1a, P1b;                              // W reg-stage sets
    float nyacc = 0.0f;

#define MF(a, b, c) __builtin_amdgcn_mfma_f32_32x32x16_bf16(a, b, c, 0, 0, 0)

#define LOADAH(S, tt) { const uint4* p_ = ah_p + ((size_t)(tt) << 11); \
    S##00 = *(const short8*)(p_);       S##01 = *(const short8*)(p_ + 64); \
    S##10 = *(const short8*)(p_ + 128); S##11 = *(const short8*)(p_ + 192); }

#define LOADAL(S, tt) { const uint4* p_ = al_p + ((size_t)(tt) << 11); \
    S##00 = *(const short8*)(p_);       S##01 = *(const short8*)(p_ + 64); \
    S##10 = *(const short8*)(p_ + 128); S##11 = *(const short8*)(p_ + 192); }

#define LOADB(P, tt) { const float* p_ = bP + ((tt) << 5); \
    P##a = *(const float4*)p_; P##b = *(const float4*)(p_ + 4); }

#define STOREB(buf, P) { uint4 h_, l_; \
    splitPack2(P##a.x, P##a.y, h_.x, l_.x); \
    splitPack2(P##a.z, P##a.w, h_.y, l_.y); \
    splitPack2(P##b.x, P##b.y, h_.z, l_.z); \
    splitPack2(P##b.z, P##b.w, h_.w, l_.w); \
    BsHi[buf][wiB] = h_; BsLo[buf][wiB] = l_; \
    nyacc = fmaf(P##a.x, P##a.x, nyacc); nyacc = fmaf(P##a.y, P##a.y, nyacc); \
    nyacc = fmaf(P##a.z, P##a.z, nyacc); nyacc = fmaf(P##a.w, P##a.w, nyacc); \
    nyacc = fmaf(P##b.x, P##b.x, nyacc); nyacc = fmaf(P##b.y, P##b.y, nyacc); \
    nyacc = fmaf(P##b.z, P##b.z, nyacc); nyacc = fmaf(P##b.w, P##b.w, nyacc); }

#define LDB4(P, BUF) { \
    P##00 = *(const short8*)&(BUF)[iB00]; P##01 = *(const short8*)&(BUF)[iB01]; \
    P##10 = *(const short8*)&(BUF)[iB10]; P##11 = *(const short8*)&(BUF)[iB11]; }

// 8 MFMA, 4-independent chains (ks0 sweep then ks1 sweep; per-acc order = ks0,ks1)
#define CLUSTER(A_, B_) { \
    __builtin_amdgcn_s_setprio(1); \
    acc00 = MF(A_##00, B_##00, acc00); \
    acc01 = MF(A_##00, B_##10, acc01); \
    acc10 = MF(A_##10, B_##00, acc10); \
    acc11 = MF(A_##10, B_##10, acc11); \
    acc00 = MF(A_##01, B_##01, acc00); \
    acc01 = MF(A_##01, B_##11, acc01); \
    acc10 = MF(A_##11, B_##01, acc10); \
    acc11 = MF(A_##11, B_##11, acc11); \
    __builtin_amdgcn_s_setprio(0); }

#define SBAR __builtin_amdgcn_sched_barrier(0)
#define WAIT_LGKM asm volatile("s_waitcnt lgkmcnt(0)" ::: "memory")

// One K-tile = 3 phases. Each phase: {mem issue} bar lgkm0 {8 MFMA} bar.
#define TILE(cur, tt, AHc, AHn, ALc, ALn, PBc, PBn, G1, G2) do { \
    /* phase 1: B-hi reads + A-hi(t+1) prefetch + hh */ \
    LDB4(bh, BsHi[cur]); \
    if (G1) LOADAH(AHn, (tt) + 1); \
    SBAR; __builtin_amdgcn_s_barrier(); \
    WAIT_LGKM; SBAR; \
    CLUSTER(AHc, bh); \
    SBAR; __builtin_amdgcn_s_barrier(); \
    /* phase 2: B-lo reads + W(t+2) prefetch + hl */ \
    LDB4(bl, BsLo[cur]); \
    if (G2) LOADB(PBc, (tt) + 2); \
    SBAR; __builtin_amdgcn_s_barrier(); \
    WAIT_LGKM; SBAR; \
    CLUSTER(AHc, bl); \
    SBAR; __builtin_amdgcn_s_barrier(); \
    /* phase 3: publish B(t+1) + A-lo(t+1) prefetch + lh */ \
    if (G1) { STOREB((cur) ^ 1, PBn); LOADAL(ALn, (tt) + 1); } \
    SBAR; __builtin_amdgcn_s_barrier(); \
    WAIT_LGKM; SBAR; \
    CLUSTER(ALc, bh); \
    SBAR; __builtin_amdgcn_s_barrier(); \
} while (0)

    // ---- prologue: B(0) staged to buf0, B(1)->P1, A-hi/lo(0)->set0 ----
    LOADB(P0, 0);
    LOADB(P1, 1);
    LOADAH(X0, 0);
    LOADAL(L0, 0);
    STOREB(0, P0);
    SBAR; WAIT_LGKM; SBAR;
    __builtin_amdgcn_s_barrier();

    for (int t = 0; t < 126; t += 2) {
        TILE(0, t,     X0, X1, L0, L1, P0, P1, 1, 1);
        TILE(1, t + 1, X1, X0, L1, L0, P1, P0, 1, 1);
    }
    TILE(0, 126, X0, X1, L0, L1, P0, P1, 1, 0);
    TILE(1, 127, X1, X0, L1, L0, P1, P0, 0, 0);

    // ---- fused ||w_y||: reduce 4 slot-threads per row ----
    float s = nyacc;
    s += __shfl_xor(s, 1);
    s += __shfl_xor(s, 2);
    if (sB == 0) ny_inv[rB] = 1.0f / fmaxf(sqrtf(s), 1e-12f);
    __syncthreads();

    // ---- epilogue: gate + scale + argmax ----
    // 32x32 C/D: value v of acc{mi}{ni} = S[row (v&3)+8*(v>>2)+4*(lane>>5)][col lane&31]
    const int yloc0 = (wn << 6) + (lane & 31);
    const int yloc1 = yloc0 + 32;
    const float scl0 = ny_inv[yloc0], scl1 = ny_inv[yloc1];
    const int act0 = (age[y0 + yloc0] >= 1), act1 = (age[y0 + yloc1] >= 1);
    const int yb0 = y0 + yloc0, yb1 = y0 + yloc1;
    const int rbase = (wm << 6) + ((lane >> 5) << 2);

#define ARGMAX_MI(ACC0, ACC1, mibase) do { \
    _Pragma("unroll") for (int v = 0; v < 16; ++v) { \
        float bv = act0 ? ACC0[v] * scl0 : 0.0f; int bi = yb0; \
        const float v1 = act1 ? ACC1[v] * scl1 : 0.0f; \
        if (v1 > bv) { bv = v1; bi = yb1; } \
        _Pragma("unroll") for (int off = 1; off < 32; off <<= 1) { \
            const float ov = __shfl_xor(bv, off); \
            const int   oi = __shfl_xor(bi, off); \
            if (ov > bv || (ov == bv && oi < bi)) { bv = ov; bi = oi; } \
        } \
        if ((lane & 31) == 0) \
            comb[rbase + (mibase) + (v & 3) + ((v >> 2) << 3)][wn] = \
                make_float2(bv, __int_as_float(bi)); \
    } } while (0)

    ARGMAX_MI(acc00, acc01, 0);
    ARGMAX_MI(acc10, acc11, 32);

    __syncthreads();
    if (tid < 256) {
        const float2 e0 = comb[tid][0], e1 = comb[tid][1];
        const int i0 = __float_as_int(e0.y), i1 = __float_as_int(e1.y);
        const bool take1 = (e1.x > e0.x) || (e1.x == e0.x && i1 < i0);
        cand[(size_t)(b0 + tid) * 256 + blockIdx.y] = take1 ? e1 : e0;
    }
#undef MF
#undef LOADAH
#undef LOADAL
#undef LOADB
#undef STOREB
#undef LDB4
#undef CLUSTER
#undef SBAR
#undef WAIT_LGKM
#undef TILE
#undef ARGMAX_MI
}

__global__ __launch_bounds__(256) void reduce_winner(const float2* __restrict__ cand,
                                                     int* __restrict__ winner, int nChunks) {
    const int b = blockIdx.x;
    const int t = threadIdx.x;
    float bv = -INFINITY; int bi = 0x7fffffff;
    for (int c = t; c < nChunks; c += 256) {
        const float2 e = cand[(size_t)b * nChunks + c];
        const int i = __float_as_int(e.y);
        if (e.x > bv || (e.x == bv && i < bi)) { bv = e.x; bi = i; }
    }
    #pragma unroll
    for (int off = 32; off; off >>= 1) {
        const float ov = __shfl_xor(bv, off);
        const int   oi = __shfl_xor(bi, off);
        if (ov > bv || (ov == bv && oi < bi)) { bv = ov; bi = oi; }
    }
    __shared__ float sv[4]; __shared__ int si[4];
    if ((t & 63) == 0) { sv[t >> 6] = bv; si[t >> 6] = bi; }
    __syncthreads();
    if (t == 0) {
        #pragma unroll
        for (int wv = 1; wv < 4; ++wv)
            if (sv[wv] > bv || (sv[wv] == bv && si[wv] < bi)) { bv = sv[wv]; bi = si[wv]; }
        winner[b] = bi;
    }
}

__global__ __launch_bounds__(256) void gather_out(const float* __restrict__ y2z,
                                                  const float* __restrict__ nz,
                                                  const int* __restrict__ winner,
                                                  float* __restrict__ out,
                                                  int B, int Z, int Y) {
    const int g = blockIdx.x * 256 + threadIdx.x;
    if (g >= B * Z) return;
    const int b = g / Z, z = g - b * Z;
    out[g] = y2z[(size_t)z * Y + winner[b]] / fmaxf(nz[z], 1e-12f);
}

extern "C" void kernel_launch(void* const* d_in, const int* in_sizes, int n_in,
                              void* d_out, int out_size, void* d_ws, size_t ws_size,
                              hipStream_t stream) {
    const float* x     = (const float*)d_in[0];
    const float* x2y_w = (const float*)d_in[2];
    const float* y2z_w = (const float*)d_in[3];
    const int*   y_age = (const int*)d_in[4];
    float* out = (float*)d_out;

    const int B = 512, Y = 32768, Z = 1000;
    const int nChunks = 256;

    // ws layout: cand 1MB | nz 4KB | winner 2KB | xhi 4MB | xlo 4MB
    float2* cand   = (float2*)d_ws;
    float*  nz     = (float*)(cand + (size_t)B * nChunks);
    int*    winner = (int*)(nz + 1024);
    uint4*  xhi    = (uint4*)(winner + 512);
    uint4*  xlo    = xhi + 262144;

    split_x<<<512, 512, 0, stream>>>(x, xhi, xlo);
    row_norms<<<Z, 256, 0, stream>>>(y2z_w, nz, Y);

    gemm_argmax<<<dim3(2, 256), 512, 0, stream>>>(x2y_w, xhi, xlo, y_age, cand);
    reduce_winner<<<B, 256, 0, stream>>>(cand, winner, nChunks);
    gather_out<<<(B * Z + 255) / 256, 256, 0, stream>>>(y2z_w, nz, winner, out, B, Z, Y);
}